// Round 4
// baseline (3184.450 us; speedup 1.0000x reference)
//
#include <hip/hip_runtime.h>

using bf = unsigned short;
typedef __attribute__((ext_vector_type(8))) short short8v;
typedef __attribute__((ext_vector_type(4))) float f32x4;
typedef __attribute__((ext_vector_type(4))) unsigned int u32x4;
typedef __attribute__((ext_vector_type(2))) unsigned int u32x2;

__device__ __forceinline__ float bf2f(bf u) { return __uint_as_float(((unsigned)u) << 16); }
__device__ __forceinline__ bf f2bf(float f) {
    unsigned x = __float_as_uint(f);
    x += 0x7fffu + ((x >> 16) & 1u);   // RNE
    return (bf)(x >> 16);
}

// ---------------------------------------------------------------------------
// Implicit-GEMM conv, NHWC bf16, fp32 accum. 512 threads = 8 waves (2co x 4px).
// RS==1 (downsample): LDS-free, direct per-lane global B-frags.
// RS==3: LDS-staged halo tile, XOR-swizzled ci-granules; CC==64 & NCH>1 get
// T14 register-prefetch of chunk t+1 overlapped with compute of chunk t.
// ---------------------------------------------------------------------------
template <int CI, int CC, int RS, int STRIDE, bool RELU, bool COMBINE, int LOG2W>
__global__ __launch_bounds__(512, 4) void conv_mfma(
    const bf* __restrict__ X, const bf* __restrict__ Wp,
    const float* __restrict__ bias, bf* __restrict__ Y,
    const bf* __restrict__ res, const float* __restrict__ probs,
    int kidx, int Co) {
    constexpr int W = 1 << LOG2W;
    constexpr int ROWS = 128 >> LOG2W;
    constexpr int PAD = (RS == 3) ? 1 : 0;
    constexpr int IN_ROWS = (ROWS - 1) * STRIDE + RS;
    constexpr int IN_COLS = (W - 1) * STRIDE + RS;
    constexpr int NG = CC / 8;
    constexpr int HIN = W * STRIDE;
    constexpr int RSRS = RS * RS;
    constexpr int NCH = CI / CC;
    constexpr bool DIRECT = (RS == 1);
    constexpr int TG = IN_ROWS * IN_COLS * NG;
    constexpr int NITER = (TG + 511) / 512;
    constexpr bool PREF = (!DIRECT) && (CC == 64) && (NCH > 1);

    __shared__ bf sX[DIRECT ? 1 : IN_ROWS * IN_COLS * CC];

    const int tid = threadIdx.x;
    const int n = blockIdx.z;
    const int coBase = blockIdx.y << 6;
    const int r0 = blockIdx.x * ROWS;
    const size_t pixBase = (size_t)n * W * W + (size_t)r0 * W;

    bool active = true;
    if (kidx >= 0) active = (probs[n * 15 + kidx] >= 0.5f);
    if (!active) {
        if constexpr (COMBINE) {
            for (int i = tid; i < (128 * 64) / 8; i += 512) {
                size_t off = (pixBase + (i >> 3)) * Co + coBase + (i & 7) * 8;
                u32x4 v = *reinterpret_cast<const u32x4*>(res + off);
                *reinterpret_cast<u32x4*>(Y + off) = v;
            }
        }
        return;
    }

    const int lane = tid & 63;
    const int wid = tid >> 6;   // 0..7
    const int l15 = lane & 15;
    const int lq = lane >> 4;
    const int wm = wid >> 2;    // co half
    const int wn = wid & 3;     // px quarter

    f32x4 acc[2][2] = {};
    int prow[2], pcol[2];
#pragma unroll
    for (int nf = 0; nf < 2; ++nf) {
        int p = wn * 32 + nf * 16 + l15;
        prow[nf] = p >> LOG2W;
        pcol[nf] = p & (W - 1);
    }

    const bf* Xn = X + (size_t)n * HIN * HIN * CI;

    if constexpr (DIRECT) {
#pragma unroll
        for (int ch = 0; ch < NCH; ++ch) {
#pragma unroll
            for (int kk = 0; kk < CC / 32; ++kk) {
                short8v a[2], b[2];
#pragma unroll
                for (int mf = 0; mf < 2; ++mf) {
                    int co = coBase + wm * 32 + mf * 16 + l15;
                    a[mf] = *reinterpret_cast<const short8v*>(
                        Wp + ((size_t)ch * Co + co) * CC + kk * 32 + lq * 8);
                }
#pragma unroll
                for (int nf = 0; nf < 2; ++nf) {
                    // absolute input pixel = (r0 + prow)*STRIDE, pcol*STRIDE
                    b[nf] = *reinterpret_cast<const short8v*>(
                        Xn + ((size_t)((r0 + prow[nf]) * STRIDE) * HIN + pcol[nf] * STRIDE) * CI +
                        ch * CC + kk * 32 + lq * 8);
                }
#pragma unroll
                for (int mf = 0; mf < 2; ++mf)
#pragma unroll
                    for (int nf = 0; nf < 2; ++nf)
                        acc[mf][nf] = __builtin_amdgcn_mfma_f32_16x16x32_bf16(
                            a[mf], b[nf], acc[mf][nf], 0, 0, 0);
            }
        }
    } else {
        // stage chunk `ch` straight to LDS
        auto stage = [&](int ch) {
#pragma unroll
            for (int i = 0; i < NITER; ++i) {
                int g = tid + i * 512;
                bool inb = (TG % 512 == 0) ? true : (g < TG);
                if (inb) {
                    int ir = g / (IN_COLS * NG);
                    int rem = g - ir * (IN_COLS * NG);
                    int ic = rem / NG;
                    int gc = rem - ic * NG;
                    int in_r = r0 * STRIDE - PAD + ir;
                    int in_c = ic - PAD;
                    u32x4 v = {0, 0, 0, 0};
                    if ((unsigned)in_r < (unsigned)HIN && (unsigned)in_c < (unsigned)HIN)
                        v = *reinterpret_cast<const u32x4*>(
                            Xn + ((size_t)in_r * HIN + in_c) * CI + ch * CC + gc * 8);
                    int gsw = gc ^ (ic & (NG - 1));
                    *reinterpret_cast<u32x4*>(&sX[((ir * IN_COLS + ic) * NG + gsw) * 8]) = v;
                }
            }
        };

        auto compute = [&](int ch) {
            if constexpr (CC >= 32) {
#pragma unroll
                for (int j = 0; j < RSRS; ++j) {
                    const int dh = j / RS;
                    const int dw = j % RS;
#pragma unroll
                    for (int kk = 0; kk < CC / 32; ++kk) {
                        short8v a[2], b[2];
#pragma unroll
                        for (int mf = 0; mf < 2; ++mf) {
                            int co = coBase + wm * 32 + mf * 16 + l15;
                            a[mf] = *reinterpret_cast<const short8v*>(
                                Wp + (((size_t)(ch * RSRS + j) * Co + co) * CC + kk * 32 + lq * 8));
                        }
#pragma unroll
                        for (int nf = 0; nf < 2; ++nf) {
                            int ir = prow[nf] * STRIDE + dh;
                            int ic = pcol[nf] * STRIDE + dw;
                            int gk = (kk * 4 + lq) ^ (ic & (NG - 1));
                            b[nf] = *reinterpret_cast<const short8v*>(
                                &sX[((ir * IN_COLS + ic) * NG + gk) * 8]);
                        }
#pragma unroll
                        for (int mf = 0; mf < 2; ++mf)
#pragma unroll
                            for (int nf = 0; nf < 2; ++nf)
                                acc[mf][nf] = __builtin_amdgcn_mfma_f32_16x16x32_bf16(
                                    a[mf], b[nf], acc[mf][nf], 0, 0, 0);
                    }
                }
            } else {
                // CC==8 seed: K padded 72->96, per-lane tap j = kt*4 + lq
#pragma unroll
                for (int kt = 0; kt < 3; ++kt) {
                    int j = kt * 4 + lq;
                    int jj = (j < 9) ? j : 0;
                    int dh = jj / 3, dw = jj % 3;
                    short8v a[2], b[2];
#pragma unroll
                    for (int mf = 0; mf < 2; ++mf) {
                        int co = coBase + wm * 32 + mf * 16 + l15;
                        a[mf] = *reinterpret_cast<const short8v*>(Wp + ((size_t)j * Co + co) * 8);
                    }
#pragma unroll
                    for (int nf = 0; nf < 2; ++nf) {
                        int ir = prow[nf] + dh;
                        int ic = pcol[nf] + dw;
                        b[nf] = *reinterpret_cast<const short8v*>(&sX[(ir * IN_COLS + ic) * 8]);
                    }
#pragma unroll
                    for (int mf = 0; mf < 2; ++mf)
#pragma unroll
                        for (int nf = 0; nf < 2; ++nf)
                            acc[mf][nf] = __builtin_amdgcn_mfma_f32_16x16x32_bf16(
                                a[mf], b[nf], acc[mf][nf], 0, 0, 0);
                }
            }
        };

        if constexpr (PREF) {
            u32x4 pf[NITER];
            stage(0);
            __syncthreads();
#pragma unroll
            for (int ch = 0; ch < NCH; ++ch) {
                if (ch + 1 < NCH) {
                    // issue next chunk's global loads (in flight during compute)
#pragma unroll
                    for (int i = 0; i < NITER; ++i) {
                        int g = tid + i * 512;
                        bool inb = (TG % 512 == 0) ? true : (g < TG);
                        u32x4 v = {0, 0, 0, 0};
                        if (inb) {
                            int ir = g / (IN_COLS * NG);
                            int rem = g - ir * (IN_COLS * NG);
                            int ic = rem / NG;
                            int gc = rem - ic * NG;
                            int in_r = r0 * STRIDE - PAD + ir;
                            int in_c = ic - PAD;
                            if ((unsigned)in_r < (unsigned)HIN && (unsigned)in_c < (unsigned)HIN)
                                v = *reinterpret_cast<const u32x4*>(
                                    Xn + ((size_t)in_r * HIN + in_c) * CI + (ch + 1) * CC + gc * 8);
                        }
                        pf[i] = v;
                    }
                }
                compute(ch);
                if (ch + 1 < NCH) {
                    __syncthreads();
#pragma unroll
                    for (int i = 0; i < NITER; ++i) {
                        int g = tid + i * 512;
                        bool inb = (TG % 512 == 0) ? true : (g < TG);
                        if (inb) {
                            int ir = g / (IN_COLS * NG);
                            int rem = g - ir * (IN_COLS * NG);
                            int ic = rem / NG;
                            int gc = rem - ic * NG;
                            int gsw = gc ^ (ic & (NG - 1));
                            *reinterpret_cast<u32x4*>(
                                &sX[((ir * IN_COLS + ic) * NG + gsw) * 8]) = pf[i];
                        }
                    }
                    __syncthreads();
                }
            }
        } else {
#pragma unroll
            for (int ch = 0; ch < NCH; ++ch) {
                if (ch) __syncthreads();
                stage(ch);
                __syncthreads();
                compute(ch);
            }
        }
    }

    // epilogue: bias (+res, relu, mask), store NHWC bf16
#pragma unroll
    for (int mf = 0; mf < 2; ++mf) {
        int co0 = coBase + wm * 32 + mf * 16 + lq * 4;
        float4 b4 = *reinterpret_cast<const float4*>(bias + co0);
        float bb[4] = {b4.x, b4.y, b4.z, b4.w};
#pragma unroll
        for (int nf = 0; nf < 2; ++nf) {
            int p = wn * 32 + nf * 16 + l15;
            size_t off = (pixBase + p) * Co + co0;
            float v[4];
#pragma unroll
            for (int i = 0; i < 4; ++i) v[i] = acc[mf][nf][i] + bb[i];
            if constexpr (COMBINE) {
                u32x2 r2 = *reinterpret_cast<const u32x2*>(res + off);
                bf rr[4] = {(bf)(r2[0] & 0xffff), (bf)(r2[0] >> 16),
                            (bf)(r2[1] & 0xffff), (bf)(r2[1] >> 16)};
#pragma unroll
                for (int i = 0; i < 4; ++i) v[i] = fmaxf(v[i] + bf2f(rr[i]), 0.f);
            }
            if constexpr (RELU) {
#pragma unroll
                for (int i = 0; i < 4; ++i) v[i] = fmaxf(v[i], 0.f);
            }
            unsigned lo = (unsigned)f2bf(v[0]) | ((unsigned)f2bf(v[1]) << 16);
            unsigned hi = (unsigned)f2bf(v[2]) | ((unsigned)f2bf(v[3]) << 16);
            u32x2 o2 = {lo, hi};
            *reinterpret_cast<u32x2*>(Y + off) = o2;
        }
    }
}

// ---------------------------------------------------------------------------
// Fused repack: all weight tensors OIHW fp32 -> [chunk][tap][co][ci] bf16
// in ONE dispatch (34 segments passed by value).
#define NSEG 34
struct Seg {
    const float* src;
    bf* dst;
    int Co, Ci, RSRS, CC, JPAD, blk0;
};
struct SegArgs {
    Seg s[NSEG];
};
__global__ void repack_all(SegArgs A) {
    int b = blockIdx.x;
    int lo = 0;
#pragma unroll 1
    for (int i = 1; i < NSEG; ++i)
        if (A.s[i].blk0 <= b) lo = i;
    Seg sg = A.s[lo];
    int NCH_ = (sg.Ci + sg.CC - 1) / sg.CC;
    size_t total = (size_t)NCH_ * sg.JPAD * sg.Co * sg.CC;
    size_t idx = (size_t)(b - sg.blk0) * 256 + threadIdx.x;
    if (idx >= total) return;
    int cw = (int)(idx % sg.CC);
    int co = (int)((idx / sg.CC) % sg.Co);
    int j = (int)((idx / ((size_t)sg.CC * sg.Co)) % sg.JPAD);
    int ch = (int)(idx / ((size_t)sg.CC * sg.Co * sg.JPAD));
    int ci = ch * sg.CC + cw;
    float v = 0.f;
    if (ci < sg.Ci && j < sg.RSRS) v = sg.src[((size_t)co * sg.Ci + ci) * sg.RSRS + j];
    sg.dst[idx] = f2bf(v);
}

// NCHW fp32 [128,3,64,64] -> NHWC bf16 [128,64,64,8] (channels zero-padded)
__global__ void cvt_in(const float* __restrict__ in, bf* __restrict__ out) {
    size_t idx = (size_t)blockIdx.x * 256 + threadIdx.x;
    int c = (int)(idx & 7);
    size_t pix = idx >> 3;
    int w = (int)(pix & 63);
    int h = (int)((pix >> 6) & 63);
    int n = (int)(pix >> 12);
    float v = 0.f;
    if (c < 3) v = in[(((size_t)n * 3 + c) * 64 + h) * 64 + w];
    out[idx] = f2bf(v);
}

// [NB,256px,256ch] bf16 -> mean over px -> [NB,256] f32. Vectorized 16B loads.
__global__ void pool_k(const bf* __restrict__ X, float* __restrict__ pooled) {
    __shared__ float red[8][256];
    int n = blockIdx.x;
    int g = threadIdx.x & 31;      // ci granule (8 ch)
    int slice = threadIdx.x >> 5;  // 8 pixel slices of 32
    float acc[8] = {};
    for (int p = slice * 32; p < slice * 32 + 32; ++p) {
        u32x4 v = *reinterpret_cast<const u32x4*>(X + ((size_t)n * 256 + p) * 256 + g * 8);
#pragma unroll
        for (int i = 0; i < 4; ++i) {
            acc[2 * i] += bf2f((bf)(v[i] & 0xffff));
            acc[2 * i + 1] += bf2f((bf)(v[i] >> 16));
        }
    }
#pragma unroll
    for (int i = 0; i < 8; ++i) red[slice][g * 8 + i] = acc[i];
    __syncthreads();
    if (slice == 0) {
#pragma unroll
        for (int i = 0; i < 8; ++i) {
            float s = 0.f;
#pragma unroll
            for (int ss = 0; ss < 8; ++ss) s += red[ss][g * 8 + i];
            pooled[n * 256 + g * 8 + i] = s * (1.f / 256.f);
        }
    }
}

__global__ void fc_k(const float* __restrict__ pooled, const float* __restrict__ fw,
                     const float* __restrict__ fb, float* __restrict__ out) {
    __shared__ float sp[256];
    int n = blockIdx.x;
    sp[threadIdx.x] = pooled[n * 256 + threadIdx.x];
    __syncthreads();
    for (int o = threadIdx.x; o < 1000; o += 256) {
        float acc = fb[o];
        for (int k = 0; k < 256; ++k) acc += sp[k] * fw[(size_t)o * 256 + k];
        out[(size_t)n * 1000 + o] = acc;
    }
}

// ---------------------------------------------------------------------------
template <int CIN, int COUT, int S, int LW, int CC1>
static void run_group(hipStream_t st, bf* X, bf* H, bf* OUT,
                      bf* wp_ds, const float* ds_b, bf* wp_w1, const float* b1,
                      bf* wp_w2, const float* b2, bf* const* wp_rw1, const float* rb1,
                      bf* const* wp_rw2, const float* rb2, const float* probs_c,
                      int kbase, int NB) {
    constexpr int Wo = 1 << LW;
    dim3 grid((Wo * Wo) / 128, COUT / 64, NB);
    conv_mfma<CIN, 64, 1, S, false, false, LW><<<grid, 512, 0, st>>>(
        X, wp_ds, ds_b, OUT, nullptr, nullptr, -1, COUT);
    conv_mfma<CIN, CC1, 3, S, true, false, LW><<<grid, 512, 0, st>>>(
        X, wp_w1, b1, H, nullptr, probs_c, kbase, COUT);
    conv_mfma<COUT, 64, 3, 1, false, true, LW><<<grid, 512, 0, st>>>(
        H, wp_w2, b2, OUT, OUT, probs_c, kbase, COUT);
    for (int j = 0; j < 4; ++j) {
        conv_mfma<COUT, 64, 3, 1, true, false, LW><<<grid, 512, 0, st>>>(
            OUT, wp_rw1[j], rb1 + j * COUT, H, nullptr, probs_c, kbase + 1 + j, COUT);
        conv_mfma<COUT, 64, 3, 1, false, true, LW><<<grid, 512, 0, st>>>(
            H, wp_rw2[j], rb2 + j * COUT, OUT, OUT, probs_c, kbase + 1 + j, COUT);
    }
}

extern "C" void kernel_launch(void* const* d_in, const int* in_sizes, int n_in,
                              void* d_out, int out_size, void* d_ws, size_t ws_size,
                              hipStream_t stream) {
    (void)in_sizes; (void)n_in; (void)out_size;
    const float* input = (const float*)d_in[0];
    const float* probs = (const float*)d_in[1];
    const float* seed_w = (const float*)d_in[2];
    const float* seed_b = (const float*)d_in[3];
    const float* fc_w = (const float*)d_in[34];
    const float* fc_b = (const float*)d_in[35];

    char* pw = (char*)d_ws;
    auto alloc = [&](size_t bytes) -> void* {
        void* r = (void*)pw;
        pw += ((bytes + 255) & ~(size_t)255);
        return r;
    };

    bf* xin = (bf*)alloc(128ull * 64 * 64 * 8 * 2);
    float* pooled = (float*)alloc(128 * 256 * 4);

    SegArgs sa;
    int nseg = 0;
    int blkAcc = 0;
    auto pack = [&](const float* w, int Co_, int Ci_, int RSRS_, int CC_, int JPAD_) -> bf* {
        int NCH_ = (Ci_ + CC_ - 1) / CC_;
        size_t total = (size_t)NCH_ * JPAD_ * Co_ * CC_;
        bf* wp = (bf*)alloc(total * 2);
        sa.s[nseg] = {w, wp, Co_, Ci_, RSRS_, CC_, JPAD_, blkAcc};
        blkAcc += (int)((total + 255) / 256);
        ++nseg;
        return wp;
    };

    cvt_in<<<dim3(16384), 256, 0, stream>>>(input, xin);

    bf* wpSeed = pack(seed_w, 64, 3, 9, 8, 12);
    const int cis[3] = {64, 64, 128};
    const int cos[3] = {64, 128, 256};
    const int cc1s[3] = {64, 32, 32};
    bf* wp_ds[3];
    bf* wp_w1[3];
    bf* wp_w2[3];
    bf* wp_rw1[3][4];
    bf* wp_rw2[3][4];
    const float *ds_b[3], *b1[3], *b2[3], *rb1[3], *rb2[3];
    for (int g = 0; g < 3; ++g) {
        int base = 4 + g * 10;
        const float* dsw = (const float*)d_in[base + 0];
        ds_b[g] = (const float*)d_in[base + 1];
        const float* w1 = (const float*)d_in[base + 2];
        b1[g] = (const float*)d_in[base + 3];
        const float* w2 = (const float*)d_in[base + 4];
        b2[g] = (const float*)d_in[base + 5];
        const float* rw1 = (const float*)d_in[base + 6];
        rb1[g] = (const float*)d_in[base + 7];
        const float* rw2 = (const float*)d_in[base + 8];
        rb2[g] = (const float*)d_in[base + 9];
        int Ci = cis[g], Co = cos[g];
        wp_ds[g] = pack(dsw, Co, Ci, 1, 64, 1);
        wp_w1[g] = pack(w1, Co, Ci, 9, cc1s[g], 9);
        wp_w2[g] = pack(w2, Co, Co, 9, 64, 9);
        for (int j = 0; j < 4; ++j) {
            wp_rw1[g][j] = pack(rw1 + (size_t)j * Co * Co * 9, Co, Co, 9, 64, 9);
            wp_rw2[g][j] = pack(rw2 + (size_t)j * Co * Co * 9, Co, Co, 9, 64, 9);
        }
    }
    // pad remaining segments (blk0 > total blocks -> never selected)
    for (int i = nseg; i < NSEG; ++i) sa.s[i] = {nullptr, nullptr, 1, 1, 1, 1, 1, 0x7fffffff};
    repack_all<<<dim3(blkAcc), 256, 0, stream>>>(sa);

    // ---- batch chunking to fit workspace ----
    size_t used = (size_t)(pw - (char*)d_ws);
    size_t avail = (ws_size > used) ? (ws_size - used) : 0;
    const size_t PER_IMG = 64ull * 64 * 64 * 2;  // 512 KB
    int NB = 128;
    while (NB > 8 && (size_t)3 * NB * PER_IMG + 4096 > avail) NB >>= 1;

    bf* A = (bf*)alloc((size_t)NB * PER_IMG);
    bf* Bb = (bf*)alloc((size_t)NB * PER_IMG);
    bf* C = (bf*)alloc((size_t)NB * PER_IMG);

    for (int n0 = 0; n0 < 128; n0 += NB) {
        const float* pc = probs + (size_t)n0 * 15;
        conv_mfma<8, 8, 3, 1, true, false, 6><<<dim3(32, 1, NB), 512, 0, stream>>>(
            xin + (size_t)n0 * 64 * 64 * 8, wpSeed, seed_b, A, nullptr, nullptr, -1, 64);

        run_group<64, 64, 1, 6, 64>(stream, A, Bb, C, wp_ds[0], ds_b[0], wp_w1[0], b1[0],
                                    wp_w2[0], b2[0], wp_rw1[0], rb1[0], wp_rw2[0], rb2[0],
                                    pc, 0, NB);
        run_group<64, 128, 2, 5, 32>(stream, C, Bb, A, wp_ds[1], ds_b[1], wp_w1[1], b1[1],
                                     wp_w2[1], b2[1], wp_rw1[1], rb1[1], wp_rw2[1], rb2[1],
                                     pc, 5, NB);
        run_group<128, 256, 2, 4, 32>(stream, A, Bb, C, wp_ds[2], ds_b[2], wp_w1[2], b1[2],
                                      wp_w2[2], b2[2], wp_rw1[2], rb1[2], wp_rw2[2], rb2[2],
                                      pc, 10, NB);

        pool_k<<<dim3(NB), 256, 0, stream>>>(C, pooled + (size_t)n0 * 256);
    }

    fc_k<<<dim3(128), 256, 0, stream>>>(pooled, fc_w, fc_b, (float*)d_out);
}

// Round 5
// 2040.490 us; speedup vs baseline: 1.5606x; 1.5606x over previous
//
#include <hip/hip_runtime.h>

using bf = unsigned short;
typedef __attribute__((ext_vector_type(8))) short short8v;
typedef __attribute__((ext_vector_type(4))) float f32x4;
typedef __attribute__((ext_vector_type(4))) unsigned int u32x4;
typedef __attribute__((ext_vector_type(2))) unsigned int u32x2;

__device__ __forceinline__ float bf2f(bf u) { return __uint_as_float(((unsigned)u) << 16); }
__device__ __forceinline__ bf f2bf(float f) {
    unsigned x = __float_as_uint(f);
    x += 0x7fffu + ((x >> 16) & 1u);   // RNE
    return (bf)(x >> 16);
}

// async global->LDS, 16B per lane. LDS dest must be linear in lane id
// (wave-uniform base + lane*16); global src is per-lane.
__device__ __forceinline__ void gload16(const bf* g, bf* l) {
    __builtin_amdgcn_global_load_lds(
        (const __attribute__((address_space(1))) void*)g,
        (__attribute__((address_space(3))) void*)l, 16, 0, 0);
}

// ---------------------------------------------------------------------------
// Implicit-GEMM conv, NHWC bf16, fp32 accum. 256 threads = 4 waves (2co x 2px),
// acc[2][4] -> 64co x 128px block tile.
//  A (weights) packed [chunk][tap][co][ci_in_chunk] -> contiguous 16B frags.
//  B (activations): halo tile staged to LDS via global_load_lds (linear dest);
//  bank-conflict XOR swizzle applied on the GLOBAL source granule index and
//  the LDS read granule index (same involution), per rule #21.
//  OOB halo lanes load from a 256B zero-page in ws (keeps zero padding).
//  RS==1 (downsample): LDS-free, direct per-lane global B-frags.
// COMBINE: fused  y = m ? relu(acc + bias + res) : res ; Y==res safe in-place.
// ---------------------------------------------------------------------------
template <int CI, int CC, int RS, int STRIDE, bool RELU, bool COMBINE, int LOG2W>
__global__ __launch_bounds__(256) void conv_mfma(
    const bf* __restrict__ X, const bf* __restrict__ Wp,
    const float* __restrict__ bias, bf* __restrict__ Y,
    const bf* __restrict__ res, const float* __restrict__ probs,
    const bf* __restrict__ zpage, int kidx, int Co) {
    constexpr int W = 1 << LOG2W;
    constexpr int ROWS = 128 >> LOG2W;
    constexpr int PAD = (RS == 3) ? 1 : 0;
    constexpr int IN_ROWS = (ROWS - 1) * STRIDE + RS;
    constexpr int IN_COLS = (W - 1) * STRIDE + RS;
    constexpr int NG = CC / 8;
    constexpr int HIN = W * STRIDE;
    constexpr int RSRS = RS * RS;
    constexpr int NCH = CI / CC;
    constexpr bool DIRECT = (RS == 1);
    constexpr int TG = IN_ROWS * IN_COLS * NG;
    constexpr int NITER = (TG + 255) / 256;

    __shared__ bf sX[DIRECT ? 8 : IN_ROWS * IN_COLS * CC];

    const int tid = threadIdx.x;
    const int n = blockIdx.z;
    const int coBase = blockIdx.y << 6;
    const int r0 = blockIdx.x * ROWS;
    const size_t pixBase = (size_t)n * W * W + (size_t)r0 * W;

    bool active = true;
    if (kidx >= 0) active = (probs[n * 15 + kidx] >= 0.5f);
    if (!active) {
        if constexpr (COMBINE) {
            for (int i = tid; i < (128 * 64) / 8; i += 256) {
                size_t off = (pixBase + (i >> 3)) * Co + coBase + (i & 7) * 8;
                u32x4 v = *reinterpret_cast<const u32x4*>(res + off);
                *reinterpret_cast<u32x4*>(Y + off) = v;
            }
        }
        return;
    }

    const int lane = tid & 63;
    const int wid = tid >> 6;   // 0..3
    const int l15 = lane & 15;
    const int lq = lane >> 4;
    const int wm = wid >> 1;    // co half
    const int wn = wid & 1;     // px half

    f32x4 acc[2][4] = {};
    int prow[4], pcol[4];
#pragma unroll
    for (int nf = 0; nf < 4; ++nf) {
        int p = wn * 64 + nf * 16 + l15;
        prow[nf] = p >> LOG2W;
        pcol[nf] = p & (W - 1);
    }

    const bf* Xn = X + (size_t)n * HIN * HIN * CI;

    if constexpr (DIRECT) {
#pragma unroll
        for (int ch = 0; ch < NCH; ++ch) {
#pragma unroll
            for (int kk = 0; kk < CC / 32; ++kk) {
                short8v a[2], b[4];
#pragma unroll
                for (int mf = 0; mf < 2; ++mf) {
                    int co = coBase + wm * 32 + mf * 16 + l15;
                    a[mf] = *reinterpret_cast<const short8v*>(
                        Wp + ((size_t)ch * Co + co) * CC + kk * 32 + lq * 8);
                }
#pragma unroll
                for (int nf = 0; nf < 4; ++nf) {
                    b[nf] = *reinterpret_cast<const short8v*>(
                        Xn + ((size_t)((r0 + prow[nf]) * STRIDE) * HIN + pcol[nf] * STRIDE) * CI +
                        ch * CC + kk * 32 + lq * 8);
                }
#pragma unroll
                for (int mf = 0; mf < 2; ++mf)
#pragma unroll
                    for (int nf = 0; nf < 4; ++nf)
                        acc[mf][nf] = __builtin_amdgcn_mfma_f32_16x16x32_bf16(
                            a[mf], b[nf], acc[mf][nf], 0, 0, 0);
            }
        }
    } else {
        for (int ch = 0; ch < NCH; ++ch) {
            if (ch) __syncthreads();
            // ---- stage: async global->LDS, linear dest, source-swizzled ----
#pragma unroll
            for (int i = 0; i < NITER; ++i) {
                int g = tid + i * 256;
                if (TG % 256 == 0 || g < TG) {
                    int ir = g / (IN_COLS * NG);
                    int rem = g - ir * (IN_COLS * NG);
                    int ic = rem / NG;
                    int gc = rem - ic * NG;
                    int in_r = r0 * STRIDE - PAD + ir;
                    int in_c = ic - PAD;
                    int gsrc = gc ^ (ic & (NG - 1));   // involution: slot gc holds granule gc^m
                    const bf* src = zpage;
                    if ((unsigned)in_r < (unsigned)HIN && (unsigned)in_c < (unsigned)HIN)
                        src = Xn + ((size_t)in_r * HIN + in_c) * CI + ch * CC + gsrc * 8;
                    gload16(src, &sX[(size_t)g * 8]);
                }
            }
            __syncthreads();   // drains vmcnt (gload_lds) + lgkm

            // ---- compute ----
            if constexpr (CC >= 32) {
#pragma unroll
                for (int j = 0; j < RSRS; ++j) {
                    const int dh = j / RS;
                    const int dw = j % RS;
#pragma unroll
                    for (int kk = 0; kk < CC / 32; ++kk) {
                        short8v a[2], b[4];
#pragma unroll
                        for (int mf = 0; mf < 2; ++mf) {
                            int co = coBase + wm * 32 + mf * 16 + l15;
                            a[mf] = *reinterpret_cast<const short8v*>(
                                Wp + (((size_t)(ch * RSRS + j) * Co + co) * CC + kk * 32 + lq * 8));
                        }
#pragma unroll
                        for (int nf = 0; nf < 4; ++nf) {
                            int ir = prow[nf] * STRIDE + dh;
                            int ic = pcol[nf] * STRIDE + dw;
                            int gk = (kk * 4 + lq) ^ (ic & (NG - 1));
                            b[nf] = *reinterpret_cast<const short8v*>(
                                &sX[((ir * IN_COLS + ic) * NG + gk) * 8]);
                        }
#pragma unroll
                        for (int mf = 0; mf < 2; ++mf)
#pragma unroll
                            for (int nf = 0; nf < 4; ++nf)
                                acc[mf][nf] = __builtin_amdgcn_mfma_f32_16x16x32_bf16(
                                    a[mf], b[nf], acc[mf][nf], 0, 0, 0);
                    }
                }
            } else {
                // CC==8 seed: K padded 72->96, per-lane tap j = kt*4 + lq
#pragma unroll
                for (int kt = 0; kt < 3; ++kt) {
                    int j = kt * 4 + lq;
                    int jj = (j < 9) ? j : 0;
                    int dh = jj / 3, dw = jj % 3;
                    short8v a[2], b[4];
#pragma unroll
                    for (int mf = 0; mf < 2; ++mf) {
                        int co = coBase + wm * 32 + mf * 16 + l15;
                        a[mf] = *reinterpret_cast<const short8v*>(Wp + ((size_t)j * Co + co) * 8);
                    }
#pragma unroll
                    for (int nf = 0; nf < 4; ++nf) {
                        int ir = prow[nf] + dh;
                        int ic = pcol[nf] + dw;
                        b[nf] = *reinterpret_cast<const short8v*>(&sX[(ir * IN_COLS + ic) * 8]);
                    }
#pragma unroll
                    for (int mf = 0; mf < 2; ++mf)
#pragma unroll
                        for (int nf = 0; nf < 4; ++nf)
                            acc[mf][nf] = __builtin_amdgcn_mfma_f32_16x16x32_bf16(
                                a[mf], b[nf], acc[mf][nf], 0, 0, 0);
                }
            }
        }
    }

    // epilogue: bias (+res, relu, mask), store NHWC bf16
#pragma unroll
    for (int mf = 0; mf < 2; ++mf) {
        int co0 = coBase + wm * 32 + mf * 16 + lq * 4;
        float4 b4 = *reinterpret_cast<const float4*>(bias + co0);
        float bb[4] = {b4.x, b4.y, b4.z, b4.w};
#pragma unroll
        for (int nf = 0; nf < 4; ++nf) {
            int p = wn * 64 + nf * 16 + l15;
            size_t off = (pixBase + p) * Co + co0;
            float v[4];
#pragma unroll
            for (int i = 0; i < 4; ++i) v[i] = acc[mf][nf][i] + bb[i];
            if constexpr (COMBINE) {
                u32x2 r2 = *reinterpret_cast<const u32x2*>(res + off);
                bf rr[4] = {(bf)(r2[0] & 0xffff), (bf)(r2[0] >> 16),
                            (bf)(r2[1] & 0xffff), (bf)(r2[1] >> 16)};
#pragma unroll
                for (int i = 0; i < 4; ++i) v[i] = fmaxf(v[i] + bf2f(rr[i]), 0.f);
            }
            if constexpr (RELU) {
#pragma unroll
                for (int i = 0; i < 4; ++i) v[i] = fmaxf(v[i], 0.f);
            }
            unsigned lo = (unsigned)f2bf(v[0]) | ((unsigned)f2bf(v[1]) << 16);
            unsigned hi = (unsigned)f2bf(v[2]) | ((unsigned)f2bf(v[3]) << 16);
            u32x2 o2 = {lo, hi};
            *reinterpret_cast<u32x2*>(Y + off) = o2;
        }
    }
}

// ---------------------------------------------------------------------------
// Fused repack: all weight tensors OIHW fp32 -> [chunk][tap][co][ci] bf16.
#define NSEG 34
struct Seg {
    const float* src;
    bf* dst;
    int Co, Ci, RSRS, CC, JPAD, blk0;
};
struct SegArgs {
    Seg s[NSEG];
};
__global__ void repack_all(SegArgs A) {
    int b = blockIdx.x;
    int lo = 0;
#pragma unroll 1
    for (int i = 1; i < NSEG; ++i)
        if (A.s[i].blk0 <= b) lo = i;
    Seg sg = A.s[lo];
    int NCH_ = (sg.Ci + sg.CC - 1) / sg.CC;
    size_t total = (size_t)NCH_ * sg.JPAD * sg.Co * sg.CC;
    size_t idx = (size_t)(b - sg.blk0) * 256 + threadIdx.x;
    if (idx >= total) return;
    int cw = (int)(idx % sg.CC);
    int co = (int)((idx / sg.CC) % sg.Co);
    int j = (int)((idx / ((size_t)sg.CC * sg.Co)) % sg.JPAD);
    int ch = (int)(idx / ((size_t)sg.CC * sg.Co * sg.JPAD));
    int ci = ch * sg.CC + cw;
    float v = 0.f;
    if (ci < sg.Ci && j < sg.RSRS) v = sg.src[((size_t)co * sg.Ci + ci) * sg.RSRS + j];
    sg.dst[idx] = f2bf(v);
}

// NCHW fp32 [128,3,64,64] -> NHWC bf16 [128,64,64,8] (channels zero-padded)
__global__ void cvt_in(const float* __restrict__ in, bf* __restrict__ out) {
    size_t idx = (size_t)blockIdx.x * 256 + threadIdx.x;
    int c = (int)(idx & 7);
    size_t pix = idx >> 3;
    int w = (int)(pix & 63);
    int h = (int)((pix >> 6) & 63);
    int n = (int)(pix >> 12);
    float v = 0.f;
    if (c < 3) v = in[(((size_t)n * 3 + c) * 64 + h) * 64 + w];
    out[idx] = f2bf(v);
}

__global__ void zero_k(bf* p) {
    u32x4 z = {0, 0, 0, 0};
    *reinterpret_cast<u32x4*>(p + (size_t)threadIdx.x * 8) = z;
}

// [NB,256px,256ch] bf16 -> mean over px -> [NB,256] f32.
__global__ void pool_k(const bf* __restrict__ X, float* __restrict__ pooled) {
    __shared__ float red[8][256];
    int n = blockIdx.x;
    int g = threadIdx.x & 31;
    int slice = threadIdx.x >> 5;
    float acc[8] = {};
    for (int p = slice * 32; p < slice * 32 + 32; ++p) {
        u32x4 v = *reinterpret_cast<const u32x4*>(X + ((size_t)n * 256 + p) * 256 + g * 8);
#pragma unroll
        for (int i = 0; i < 4; ++i) {
            acc[2 * i] += bf2f((bf)(v[i] & 0xffff));
            acc[2 * i + 1] += bf2f((bf)(v[i] >> 16));
        }
    }
#pragma unroll
    for (int i = 0; i < 8; ++i) red[slice][g * 8 + i] = acc[i];
    __syncthreads();
    if (slice == 0) {
#pragma unroll
        for (int i = 0; i < 8; ++i) {
            float s = 0.f;
#pragma unroll
            for (int ss = 0; ss < 8; ++ss) s += red[ss][g * 8 + i];
            pooled[n * 256 + g * 8 + i] = s * (1.f / 256.f);
        }
    }
}

__global__ void fc_k(const float* __restrict__ pooled, const float* __restrict__ fw,
                     const float* __restrict__ fb, float* __restrict__ out) {
    __shared__ float sp[256];
    int n = blockIdx.x;
    sp[threadIdx.x] = pooled[n * 256 + threadIdx.x];
    __syncthreads();
    for (int o = threadIdx.x; o < 1000; o += 256) {
        float acc = fb[o];
        for (int k = 0; k < 256; ++k) acc += sp[k] * fw[(size_t)o * 256 + k];
        out[(size_t)n * 1000 + o] = acc;
    }
}

// ---------------------------------------------------------------------------
template <int CIN, int COUT, int S, int LW, int CC1>
static void run_group(hipStream_t st, bf* X, bf* H, bf* OUT, const bf* zp,
                      bf* wp_ds, const float* ds_b, bf* wp_w1, const float* b1,
                      bf* wp_w2, const float* b2, bf* const* wp_rw1, const float* rb1,
                      bf* const* wp_rw2, const float* rb2, const float* probs_c,
                      int kbase, int NB) {
    constexpr int Wo = 1 << LW;
    dim3 grid((Wo * Wo) / 128, COUT / 64, NB);
    conv_mfma<CIN, 64, 1, S, false, false, LW><<<grid, 256, 0, st>>>(
        X, wp_ds, ds_b, OUT, nullptr, nullptr, zp, -1, COUT);
    conv_mfma<CIN, CC1, 3, S, true, false, LW><<<grid, 256, 0, st>>>(
        X, wp_w1, b1, H, nullptr, probs_c, zp, kbase, COUT);
    conv_mfma<COUT, 64, 3, 1, false, true, LW><<<grid, 256, 0, st>>>(
        H, wp_w2, b2, OUT, OUT, probs_c, zp, kbase, COUT);
    for (int j = 0; j < 4; ++j) {
        conv_mfma<COUT, 64, 3, 1, true, false, LW><<<grid, 256, 0, st>>>(
            OUT, wp_rw1[j], rb1 + j * COUT, H, nullptr, probs_c, zp, kbase + 1 + j, COUT);
        conv_mfma<COUT, 64, 3, 1, false, true, LW><<<grid, 256, 0, st>>>(
            H, wp_rw2[j], rb2 + j * COUT, OUT, OUT, probs_c, zp, kbase + 1 + j, COUT);
    }
}

extern "C" void kernel_launch(void* const* d_in, const int* in_sizes, int n_in,
                              void* d_out, int out_size, void* d_ws, size_t ws_size,
                              hipStream_t stream) {
    (void)in_sizes; (void)n_in; (void)out_size;
    const float* input = (const float*)d_in[0];
    const float* probs = (const float*)d_in[1];
    const float* seed_w = (const float*)d_in[2];
    const float* seed_b = (const float*)d_in[3];
    const float* fc_w = (const float*)d_in[34];
    const float* fc_b = (const float*)d_in[35];

    char* pw = (char*)d_ws;
    auto alloc = [&](size_t bytes) -> void* {
        void* r = (void*)pw;
        pw += ((bytes + 255) & ~(size_t)255);
        return r;
    };

    bf* xin = (bf*)alloc(128ull * 64 * 64 * 8 * 2);
    float* pooled = (float*)alloc(128 * 256 * 4);
    bf* zpage = (bf*)alloc(256);   // zero-page for OOB halo loads

    SegArgs sa;
    int nseg = 0;
    int blkAcc = 0;
    auto pack = [&](const float* w, int Co_, int Ci_, int RSRS_, int CC_, int JPAD_) -> bf* {
        int NCH_ = (Ci_ + CC_ - 1) / CC_;
        size_t total = (size_t)NCH_ * JPAD_ * Co_ * CC_;
        bf* wp = (bf*)alloc(total * 2);
        sa.s[nseg] = {w, wp, Co_, Ci_, RSRS_, CC_, JPAD_, blkAcc};
        blkAcc += (int)((total + 255) / 256);
        ++nseg;
        return wp;
    };

    zero_k<<<dim3(1), 16, 0, stream>>>(zpage);
    cvt_in<<<dim3(16384), 256, 0, stream>>>(input, xin);

    bf* wpSeed = pack(seed_w, 64, 3, 9, 8, 12);
    const int cis[3] = {64, 64, 128};
    const int cos[3] = {64, 128, 256};
    const int cc1s[3] = {64, 32, 32};
    bf* wp_ds[3];
    bf* wp_w1[3];
    bf* wp_w2[3];
    bf* wp_rw1[3][4];
    bf* wp_rw2[3][4];
    const float *ds_b[3], *b1[3], *b2[3], *rb1[3], *rb2[3];
    for (int g = 0; g < 3; ++g) {
        int base = 4 + g * 10;
        const float* dsw = (const float*)d_in[base + 0];
        ds_b[g] = (const float*)d_in[base + 1];
        const float* w1 = (const float*)d_in[base + 2];
        b1[g] = (const float*)d_in[base + 3];
        const float* w2 = (const float*)d_in[base + 4];
        b2[g] = (const float*)d_in[base + 5];
        const float* rw1 = (const float*)d_in[base + 6];
        rb1[g] = (const float*)d_in[base + 7];
        const float* rw2 = (const float*)d_in[base + 8];
        rb2[g] = (const float*)d_in[base + 9];
        int Ci = cis[g], Co = cos[g];
        wp_ds[g] = pack(dsw, Co, Ci, 1, 64, 1);
        wp_w1[g] = pack(w1, Co, Ci, 9, cc1s[g], 9);
        wp_w2[g] = pack(w2, Co, Co, 9, 64, 9);
        for (int j = 0; j < 4; ++j) {
            wp_rw1[g][j] = pack(rw1 + (size_t)j * Co * Co * 9, Co, Co, 9, 64, 9);
            wp_rw2[g][j] = pack(rw2 + (size_t)j * Co * Co * 9, Co, Co, 9, 64, 9);
        }
    }
    for (int i = nseg; i < NSEG; ++i) sa.s[i] = {nullptr, nullptr, 1, 1, 1, 1, 1, 0x7fffffff};
    repack_all<<<dim3(blkAcc), 256, 0, stream>>>(sa);

    // ---- batch chunking to fit workspace ----
    size_t used = (size_t)(pw - (char*)d_ws);
    size_t avail = (ws_size > used) ? (ws_size - used) : 0;
    const size_t PER_IMG = 64ull * 64 * 64 * 2;  // 512 KB
    int NB = 128;
    while (NB > 8 && (size_t)3 * NB * PER_IMG + 4096 > avail) NB >>= 1;

    bf* A = (bf*)alloc((size_t)NB * PER_IMG);
    bf* Bb = (bf*)alloc((size_t)NB * PER_IMG);
    bf* C = (bf*)alloc((size_t)NB * PER_IMG);

    for (int n0 = 0; n0 < 128; n0 += NB) {
        const float* pc = probs + (size_t)n0 * 15;
        conv_mfma<8, 8, 3, 1, true, false, 6><<<dim3(32, 1, NB), 256, 0, stream>>>(
            xin + (size_t)n0 * 64 * 64 * 8, wpSeed, seed_b, A, nullptr, nullptr, zpage, -1, 64);

        run_group<64, 64, 1, 6, 64>(stream, A, Bb, C, zpage, wp_ds[0], ds_b[0], wp_w1[0], b1[0],
                                    wp_w2[0], b2[0], wp_rw1[0], rb1[0], wp_rw2[0], rb2[0],
                                    pc, 0, NB);
        run_group<64, 128, 2, 5, 32>(stream, C, Bb, A, zpage, wp_ds[1], ds_b[1], wp_w1[1], b1[1],
                                     wp_w2[1], b2[1], wp_rw1[1], rb1[1], wp_rw2[1], rb2[1],
                                     pc, 5, NB);
        run_group<128, 256, 2, 4, 32>(stream, A, Bb, C, zpage, wp_ds[2], ds_b[2], wp_w1[2], b1[2],
                                      wp_w2[2], b2[2], wp_rw1[2], rb1[2], wp_rw2[2], rb2[2],
                                      pc, 10, NB);

        pool_k<<<dim3(NB), 256, 0, stream>>>(C, pooled + (size_t)n0 * 256);
    }

    fc_k<<<dim3(128), 256, 0, stream>>>(pooled, fc_w, fc_b, (float*)d_out);
}

// Round 6
// 2019.726 us; speedup vs baseline: 1.5767x; 1.0103x over previous
//
#include <hip/hip_runtime.h>

using bf = unsigned short;
typedef __attribute__((ext_vector_type(8))) short short8v;
typedef __attribute__((ext_vector_type(4))) float f32x4;
typedef __attribute__((ext_vector_type(4))) unsigned int u32x4;
typedef __attribute__((ext_vector_type(2))) unsigned int u32x2;

__device__ __forceinline__ float bf2f(bf u) { return __uint_as_float(((unsigned)u) << 16); }
__device__ __forceinline__ bf f2bf(float f) {
    unsigned x = __float_as_uint(f);
    x += 0x7fffu + ((x >> 16) & 1u);   // RNE
    return (bf)(x >> 16);
}

// async global->LDS, 16B per lane. LDS dest linear in lane id; global src per-lane.
__device__ __forceinline__ void gload16(const bf* g, bf* l) {
    __builtin_amdgcn_global_load_lds(
        (const __attribute__((address_space(1))) void*)g,
        (__attribute__((address_space(3))) void*)l, 16, 0, 0);
}

// ---------------------------------------------------------------------------
// Implicit-GEMM conv, NHWC bf16, fp32 accum. 256 threads = 4 waves (2co x 2px),
// acc[2][4] -> 64co x 128px block tile.
//  A (weights) packed [chunk][tap][co][ci_in_chunk] -> contiguous 16B frags.
//  B: halo tile staged to LDS via global_load_lds (linear dest); XOR swizzle
//  applied on global source granule + LDS read granule (same involution).
//  OOB halo lanes read a 256B zero-page.
//  DBUF (NCH>1, fits 64KB): issue chunk ch+1's gload_lds BEFORE compute(ch);
//  the end-of-chunk barrier drain overlaps staging latency with MFMA (T3-min).
//  CMB: 0 = plain (+optional relu), 2 = in-place residual combine
//       y = m ? relu(acc+bias+y) : y  -> masked blocks exit with NO traffic.
// ---------------------------------------------------------------------------
template <int CI, int CC, int RS, int STRIDE, bool RELU, int CMB, int LOG2W>
__global__ __launch_bounds__(256, 3) void conv_mfma(
    const bf* __restrict__ X, const bf* __restrict__ Wp,
    const float* __restrict__ bias, bf* __restrict__ Y,
    const bf* __restrict__ res, const float* __restrict__ probs,
    const bf* __restrict__ zpage, int kidx, int Co) {
    constexpr int W = 1 << LOG2W;
    constexpr int ROWS = 128 >> LOG2W;
    constexpr int PAD = (RS == 3) ? 1 : 0;
    constexpr int IN_ROWS = (ROWS - 1) * STRIDE + RS;
    constexpr int IN_COLS = (W - 1) * STRIDE + RS;
    constexpr int NG = CC / 8;
    constexpr int HIN = W * STRIDE;
    constexpr int RSRS = RS * RS;
    constexpr int NCH = CI / CC;
    constexpr bool DIRECT = (RS == 1);
    constexpr int TG = IN_ROWS * IN_COLS * NG;
    constexpr int NITER = (TG + 255) / 256;
    constexpr int HALF = IN_ROWS * IN_COLS * CC;
    constexpr bool DBUF = (!DIRECT) && (NCH > 1) && (2 * HALF * 2 <= 65536);

    __shared__ bf sX[DIRECT ? 8 : (DBUF ? 2 * HALF : HALF)];

    const int tid = threadIdx.x;
    const int n = blockIdx.z;
    const int coBase = blockIdx.y << 6;
    const int r0 = blockIdx.x * ROWS;
    const size_t pixBase = (size_t)n * W * W + (size_t)r0 * W;

    bool active = true;
    if (kidx >= 0) active = (probs[n * 15 + kidx] >= 0.5f);
    if (!active) return;   // CMB==2: Y==res, output already correct. CMB==0: unused output.

    const int lane = tid & 63;
    const int wid = tid >> 6;   // 0..3
    const int l15 = lane & 15;
    const int lq = lane >> 4;
    const int wm = wid >> 1;    // co half
    const int wn = wid & 1;     // px half

    f32x4 acc[2][4] = {};
    int prow[4], pcol[4];
#pragma unroll
    for (int nf = 0; nf < 4; ++nf) {
        int p = wn * 64 + nf * 16 + l15;
        prow[nf] = p >> LOG2W;
        pcol[nf] = p & (W - 1);
    }

    const bf* Xn = X + (size_t)n * HIN * HIN * CI;

    if constexpr (DIRECT) {
#pragma unroll
        for (int ch = 0; ch < NCH; ++ch) {
#pragma unroll
            for (int kk = 0; kk < CC / 32; ++kk) {
                short8v a[2], b[4];
#pragma unroll
                for (int mf = 0; mf < 2; ++mf) {
                    int co = coBase + wm * 32 + mf * 16 + l15;
                    a[mf] = *reinterpret_cast<const short8v*>(
                        Wp + ((size_t)ch * Co + co) * CC + kk * 32 + lq * 8);
                }
#pragma unroll
                for (int nf = 0; nf < 4; ++nf) {
                    b[nf] = *reinterpret_cast<const short8v*>(
                        Xn + ((size_t)((r0 + prow[nf]) * STRIDE) * HIN + pcol[nf] * STRIDE) * CI +
                        ch * CC + kk * 32 + lq * 8);
                }
#pragma unroll
                for (int mf = 0; mf < 2; ++mf)
#pragma unroll
                    for (int nf = 0; nf < 4; ++nf)
                        acc[mf][nf] = __builtin_amdgcn_mfma_f32_16x16x32_bf16(
                            a[mf], b[nf], acc[mf][nf], 0, 0, 0);
            }
        }
    } else {
        auto stage = [&](int ch, bf* buf) {
#pragma unroll
            for (int i = 0; i < NITER; ++i) {
                int g = tid + i * 256;
                if (TG % 256 == 0 || g < TG) {
                    int ir = g / (IN_COLS * NG);
                    int rem = g - ir * (IN_COLS * NG);
                    int ic = rem / NG;
                    int gc = rem - ic * NG;
                    int in_r = r0 * STRIDE - PAD + ir;
                    int in_c = ic - PAD;
                    int gsrc = gc ^ (ic & (NG - 1));   // involution
                    const bf* src = zpage;
                    if ((unsigned)in_r < (unsigned)HIN && (unsigned)in_c < (unsigned)HIN)
                        src = Xn + ((size_t)in_r * HIN + in_c) * CI + ch * CC + gsrc * 8;
                    gload16(src, &buf[(size_t)g * 8]);
                }
            }
        };

        auto compute = [&](int ch, const bf* buf) {
            if constexpr (CC >= 32) {
#pragma unroll
                for (int j = 0; j < RSRS; ++j) {
                    const int dh = j / RS;
                    const int dw = j % RS;
#pragma unroll
                    for (int kk = 0; kk < CC / 32; ++kk) {
                        short8v a[2], b[4];
#pragma unroll
                        for (int mf = 0; mf < 2; ++mf) {
                            int co = coBase + wm * 32 + mf * 16 + l15;
                            a[mf] = *reinterpret_cast<const short8v*>(
                                Wp + (((size_t)(ch * RSRS + j) * Co + co) * CC + kk * 32 + lq * 8));
                        }
#pragma unroll
                        for (int nf = 0; nf < 4; ++nf) {
                            int ir = prow[nf] * STRIDE + dh;
                            int ic = pcol[nf] * STRIDE + dw;
                            int gk = (kk * 4 + lq) ^ (ic & (NG - 1));
                            b[nf] = *reinterpret_cast<const short8v*>(
                                &buf[((ir * IN_COLS + ic) * NG + gk) * 8]);
                        }
#pragma unroll
                        for (int mf = 0; mf < 2; ++mf)
#pragma unroll
                            for (int nf = 0; nf < 4; ++nf)
                                acc[mf][nf] = __builtin_amdgcn_mfma_f32_16x16x32_bf16(
                                    a[mf], b[nf], acc[mf][nf], 0, 0, 0);
                    }
                }
            } else {
                // CC==8 seed: K padded 72->96, per-lane tap j = kt*4 + lq
#pragma unroll
                for (int kt = 0; kt < 3; ++kt) {
                    int j = kt * 4 + lq;
                    int jj = (j < 9) ? j : 0;
                    int dh = jj / 3, dw = jj % 3;
                    short8v a[2], b[4];
#pragma unroll
                    for (int mf = 0; mf < 2; ++mf) {
                        int co = coBase + wm * 32 + mf * 16 + l15;
                        a[mf] = *reinterpret_cast<const short8v*>(Wp + ((size_t)j * Co + co) * 8);
                    }
#pragma unroll
                    for (int nf = 0; nf < 4; ++nf) {
                        int ir = prow[nf] + dh;
                        int ic = pcol[nf] + dw;
                        b[nf] = *reinterpret_cast<const short8v*>(&buf[(ir * IN_COLS + ic) * 8]);
                    }
#pragma unroll
                    for (int mf = 0; mf < 2; ++mf)
#pragma unroll
                        for (int nf = 0; nf < 4; ++nf)
                            acc[mf][nf] = __builtin_amdgcn_mfma_f32_16x16x32_bf16(
                                a[mf], b[nf], acc[mf][nf], 0, 0, 0);
                }
            }
        };

        if constexpr (DBUF) {
            stage(0, sX);
            __syncthreads();                 // drain: buf0 ready
#pragma unroll
            for (int ch = 0; ch < NCH; ++ch) {
                bf* cur = sX + (size_t)(ch & 1) * HALF;
                bf* nxt = sX + (size_t)((ch + 1) & 1) * HALF;
                if (ch + 1 < NCH) stage(ch + 1, nxt);   // async issue, no wait
                compute(ch, cur);
                if (ch + 1 < NCH) __syncthreads();      // drain nxt + sync
            }
        } else {
            for (int ch = 0; ch < NCH; ++ch) {
                if (ch) __syncthreads();
                stage(ch, sX);
                __syncthreads();
                compute(ch, sX);
            }
        }
    }

    // epilogue: bias (+res, relu, mask), store NHWC bf16
#pragma unroll
    for (int mf = 0; mf < 2; ++mf) {
        int co0 = coBase + wm * 32 + mf * 16 + lq * 4;
        float4 b4 = *reinterpret_cast<const float4*>(bias + co0);
        float bb[4] = {b4.x, b4.y, b4.z, b4.w};
#pragma unroll
        for (int nf = 0; nf < 4; ++nf) {
            int p = wn * 64 + nf * 16 + l15;
            size_t off = (pixBase + p) * Co + co0;
            float v[4];
#pragma unroll
            for (int i = 0; i < 4; ++i) v[i] = acc[mf][nf][i] + bb[i];
            if constexpr (CMB >= 1) {
                u32x2 r2 = *reinterpret_cast<const u32x2*>(res + off);
                bf rr[4] = {(bf)(r2[0] & 0xffff), (bf)(r2[0] >> 16),
                            (bf)(r2[1] & 0xffff), (bf)(r2[1] >> 16)};
#pragma unroll
                for (int i = 0; i < 4; ++i) v[i] = fmaxf(v[i] + bf2f(rr[i]), 0.f);
            }
            if constexpr (RELU) {
#pragma unroll
                for (int i = 0; i < 4; ++i) v[i] = fmaxf(v[i], 0.f);
            }
            unsigned lo = (unsigned)f2bf(v[0]) | ((unsigned)f2bf(v[1]) << 16);
            unsigned hi = (unsigned)f2bf(v[2]) | ((unsigned)f2bf(v[3]) << 16);
            u32x2 o2 = {lo, hi};
            *reinterpret_cast<u32x2*>(Y + off) = o2;
        }
    }
}

// ---------------------------------------------------------------------------
// Fused repack: all weight tensors OIHW fp32 -> [chunk][tap][co][ci] bf16.
#define NSEG 34
struct Seg {
    const float* src;
    bf* dst;
    int Co, Ci, RSRS, CC, JPAD, blk0;
};
struct SegArgs {
    Seg s[NSEG];
};
__global__ void repack_all(SegArgs A) {
    int b = blockIdx.x;
    int lo = 0;
#pragma unroll 1
    for (int i = 1; i < NSEG; ++i)
        if (A.s[i].blk0 <= b) lo = i;
    Seg sg = A.s[lo];
    int NCH_ = (sg.Ci + sg.CC - 1) / sg.CC;
    size_t total = (size_t)NCH_ * sg.JPAD * sg.Co * sg.CC;
    size_t idx = (size_t)(b - sg.blk0) * 256 + threadIdx.x;
    if (idx >= total) return;
    int cw = (int)(idx % sg.CC);
    int co = (int)((idx / sg.CC) % sg.Co);
    int j = (int)((idx / ((size_t)sg.CC * sg.Co)) % sg.JPAD);
    int ch = (int)(idx / ((size_t)sg.CC * sg.Co * sg.JPAD));
    int ci = ch * sg.CC + cw;
    float v = 0.f;
    if (ci < sg.Ci && j < sg.RSRS) v = sg.src[((size_t)co * sg.Ci + ci) * sg.RSRS + j];
    sg.dst[idx] = f2bf(v);
}

// NCHW fp32 [128,3,64,64] -> NHWC bf16 [128,64,64,8] (channels zero-padded)
__global__ void cvt_in(const float* __restrict__ in, bf* __restrict__ out) {
    size_t idx = (size_t)blockIdx.x * 256 + threadIdx.x;
    int c = (int)(idx & 7);
    size_t pix = idx >> 3;
    int w = (int)(pix & 63);
    int h = (int)((pix >> 6) & 63);
    int n = (int)(pix >> 12);
    float v = 0.f;
    if (c < 3) v = in[(((size_t)n * 3 + c) * 64 + h) * 64 + w];
    out[idx] = f2bf(v);
}

__global__ void zero_k(bf* p) {
    u32x4 z = {0, 0, 0, 0};
    *reinterpret_cast<u32x4*>(p + (size_t)threadIdx.x * 8) = z;
}

// [NB,256px,256ch] bf16 -> mean over px -> [NB,256] f32.
__global__ void pool_k(const bf* __restrict__ X, float* __restrict__ pooled) {
    __shared__ float red[8][256];
    int n = blockIdx.x;
    int g = threadIdx.x & 31;
    int slice = threadIdx.x >> 5;
    float acc[8] = {};
    for (int p = slice * 32; p < slice * 32 + 32; ++p) {
        u32x4 v = *reinterpret_cast<const u32x4*>(X + ((size_t)n * 256 + p) * 256 + g * 8);
#pragma unroll
        for (int i = 0; i < 4; ++i) {
            acc[2 * i] += bf2f((bf)(v[i] & 0xffff));
            acc[2 * i + 1] += bf2f((bf)(v[i] >> 16));
        }
    }
#pragma unroll
    for (int i = 0; i < 8; ++i) red[slice][g * 8 + i] = acc[i];
    __syncthreads();
    if (slice == 0) {
#pragma unroll
        for (int i = 0; i < 8; ++i) {
            float s = 0.f;
#pragma unroll
            for (int ss = 0; ss < 8; ++ss) s += red[ss][g * 8 + i];
            pooled[n * 256 + g * 8 + i] = s * (1.f / 256.f);
        }
    }
}

__global__ void fc_k(const float* __restrict__ pooled, const float* __restrict__ fw,
                     const float* __restrict__ fb, float* __restrict__ out) {
    __shared__ float sp[256];
    int n = blockIdx.x;
    sp[threadIdx.x] = pooled[n * 256 + threadIdx.x];
    __syncthreads();
    for (int o = threadIdx.x; o < 1000; o += 256) {
        float acc = fb[o];
        for (int k = 0; k < 256; ++k) acc += sp[k] * fw[(size_t)o * 256 + k];
        out[(size_t)n * 1000 + o] = acc;
    }
}

// ---------------------------------------------------------------------------
template <int CIN, int COUT, int S, int LW, int CC1>
static void run_group(hipStream_t st, bf* X, bf* H, bf* OUT, const bf* zp,
                      bf* wp_ds, const float* ds_b, bf* wp_w1, const float* b1,
                      bf* wp_w2, const float* b2, bf* const* wp_rw1, const float* rb1,
                      bf* const* wp_rw2, const float* rb2, const float* probs_c,
                      int kbase, int NB) {
    constexpr int Wo = 1 << LW;
    dim3 grid((Wo * Wo) / 128, COUT / 64, NB);
    conv_mfma<CIN, 64, 1, S, false, 0, LW><<<grid, 256, 0, st>>>(
        X, wp_ds, ds_b, OUT, nullptr, nullptr, zp, -1, COUT);
    conv_mfma<CIN, CC1, 3, S, true, 0, LW><<<grid, 256, 0, st>>>(
        X, wp_w1, b1, H, nullptr, probs_c, zp, kbase, COUT);
    conv_mfma<COUT, 64, 3, 1, false, 2, LW><<<grid, 256, 0, st>>>(
        H, wp_w2, b2, OUT, OUT, probs_c, zp, kbase, COUT);
    for (int j = 0; j < 4; ++j) {
        conv_mfma<COUT, 64, 3, 1, true, 0, LW><<<grid, 256, 0, st>>>(
            OUT, wp_rw1[j], rb1 + j * COUT, H, nullptr, probs_c, zp, kbase + 1 + j, COUT);
        conv_mfma<COUT, 64, 3, 1, false, 2, LW><<<grid, 256, 0, st>>>(
            H, wp_rw2[j], rb2 + j * COUT, OUT, OUT, probs_c, zp, kbase + 1 + j, COUT);
    }
}

extern "C" void kernel_launch(void* const* d_in, const int* in_sizes, int n_in,
                              void* d_out, int out_size, void* d_ws, size_t ws_size,
                              hipStream_t stream) {
    (void)in_sizes; (void)n_in; (void)out_size;
    const float* input = (const float*)d_in[0];
    const float* probs = (const float*)d_in[1];
    const float* seed_w = (const float*)d_in[2];
    const float* seed_b = (const float*)d_in[3];
    const float* fc_w = (const float*)d_in[34];
    const float* fc_b = (const float*)d_in[35];

    char* pw = (char*)d_ws;
    auto alloc = [&](size_t bytes) -> void* {
        void* r = (void*)pw;
        pw += ((bytes + 255) & ~(size_t)255);
        return r;
    };

    bf* xin = (bf*)alloc(128ull * 64 * 64 * 8 * 2);
    float* pooled = (float*)alloc(128 * 256 * 4);
    bf* zpage = (bf*)alloc(256);   // zero-page for OOB halo loads

    SegArgs sa;
    int nseg = 0;
    int blkAcc = 0;
    auto pack = [&](const float* w, int Co_, int Ci_, int RSRS_, int CC_, int JPAD_) -> bf* {
        int NCH_ = (Ci_ + CC_ - 1) / CC_;
        size_t total = (size_t)NCH_ * JPAD_ * Co_ * CC_;
        bf* wp = (bf*)alloc(total * 2);
        sa.s[nseg] = {w, wp, Co_, Ci_, RSRS_, CC_, JPAD_, blkAcc};
        blkAcc += (int)((total + 255) / 256);
        ++nseg;
        return wp;
    };

    zero_k<<<dim3(1), 16, 0, stream>>>(zpage);
    cvt_in<<<dim3(16384), 256, 0, stream>>>(input, xin);

    bf* wpSeed = pack(seed_w, 64, 3, 9, 8, 12);
    const int cis[3] = {64, 64, 128};
    const int cos[3] = {64, 128, 256};
    const int cc1s[3] = {64, 32, 32};
    bf* wp_ds[3];
    bf* wp_w1[3];
    bf* wp_w2[3];
    bf* wp_rw1[3][4];
    bf* wp_rw2[3][4];
    const float *ds_b[3], *b1[3], *b2[3], *rb1[3], *rb2[3];
    for (int g = 0; g < 3; ++g) {
        int base = 4 + g * 10;
        const float* dsw = (const float*)d_in[base + 0];
        ds_b[g] = (const float*)d_in[base + 1];
        const float* w1 = (const float*)d_in[base + 2];
        b1[g] = (const float*)d_in[base + 3];
        const float* w2 = (const float*)d_in[base + 4];
        b2[g] = (const float*)d_in[base + 5];
        const float* rw1 = (const float*)d_in[base + 6];
        rb1[g] = (const float*)d_in[base + 7];
        const float* rw2 = (const float*)d_in[base + 8];
        rb2[g] = (const float*)d_in[base + 9];
        int Ci = cis[g], Co = cos[g];
        wp_ds[g] = pack(dsw, Co, Ci, 1, 64, 1);
        wp_w1[g] = pack(w1, Co, Ci, 9, cc1s[g], 9);
        wp_w2[g] = pack(w2, Co, Co, 9, 64, 9);
        for (int j = 0; j < 4; ++j) {
            wp_rw1[g][j] = pack(rw1 + (size_t)j * Co * Co * 9, Co, Co, 9, 64, 9);
            wp_rw2[g][j] = pack(rw2 + (size_t)j * Co * Co * 9, Co, Co, 9, 64, 9);
        }
    }
    for (int i = nseg; i < NSEG; ++i) sa.s[i] = {nullptr, nullptr, 1, 1, 1, 1, 1, 0x7fffffff};
    repack_all<<<dim3(blkAcc), 256, 0, stream>>>(sa);

    // ---- batch chunking to fit workspace ----
    size_t used = (size_t)(pw - (char*)d_ws);
    size_t avail = (ws_size > used) ? (ws_size - used) : 0;
    const size_t PER_IMG = 64ull * 64 * 64 * 2;  // 512 KB
    int NB = 128;
    while (NB > 8 && (size_t)3 * NB * PER_IMG + 4096 > avail) NB >>= 1;

    bf* A = (bf*)alloc((size_t)NB * PER_IMG);
    bf* Bb = (bf*)alloc((size_t)NB * PER_IMG);
    bf* C = (bf*)alloc((size_t)NB * PER_IMG);

    for (int n0 = 0; n0 < 128; n0 += NB) {
        const float* pc = probs + (size_t)n0 * 15;
        conv_mfma<8, 8, 3, 1, true, 0, 6><<<dim3(32, 1, NB), 256, 0, stream>>>(
            xin + (size_t)n0 * 64 * 64 * 8, wpSeed, seed_b, A, nullptr, nullptr, zpage, -1, 64);

        run_group<64, 64, 1, 6, 64>(stream, A, Bb, C, zpage, wp_ds[0], ds_b[0], wp_w1[0], b1[0],
                                    wp_w2[0], b2[0], wp_rw1[0], rb1[0], wp_rw2[0], rb2[0],
                                    pc, 0, NB);
        run_group<64, 128, 2, 5, 32>(stream, C, Bb, A, zpage, wp_ds[1], ds_b[1], wp_w1[1], b1[1],
                                     wp_w2[1], b2[1], wp_rw1[1], rb1[1], wp_rw2[1], rb2[1],
                                     pc, 5, NB);
        run_group<128, 256, 2, 4, 32>(stream, A, Bb, C, zpage, wp_ds[2], ds_b[2], wp_w1[2], b1[2],
                                      wp_w2[2], b2[2], wp_rw1[2], rb1[2], wp_rw2[2], rb2[2],
                                      pc, 10, NB);

        pool_k<<<dim3(NB), 256, 0, stream>>>(C, pooled + (size_t)n0 * 256);
    }

    fc_k<<<dim3(128), 256, 0, stream>>>(pooled, fc_w, fc_b, (float*)d_out);
}